// Round 1
// baseline (116.834 us; speedup 1.0000x reference)
//
#include <hip/hip_runtime.h>

#define BATCH 8
#define CH    64
#define H     128
#define W     128
#define TW    32
#define TH    8
#define HWID  (TW + 2)            // 34
#define HHGT  (TH + 2)            // 10
#define HALO_N (HWID * HHGT)      // 340

__device__ __forceinline__ float sigmoidf_(float v) {
    return 1.0f / (1.0f + __expf(-v));
}

__global__ __launch_bounds__(256) void maxsig_kernel(
    const float* __restrict__ x,
    const float* __restrict__ weight,
    const float* __restrict__ bias,
    const float* __restrict__ wcp,
    const float* __restrict__ wmp,
    float* __restrict__ out)
{
    __shared__ float sm[HALO_N];

    const int tid = threadIdx.x;
    const int tx  = tid & (TW - 1);
    const int ty  = tid >> 5;
    const int bx  = blockIdx.x;   // W / TW = 4
    const int by  = blockIdx.y;   // H / TH = 16
    const int b   = blockIdx.z;   // BATCH

    // ---- per-thread halo slots (channel-invariant geometry) ----
    const int i0 = tid;
    const int i1 = tid + 256;
    const bool has1 = (i1 < HALO_N);

    int yy0 = i0 / HWID, xx0 = i0 - yy0 * HWID;
    int sy0 = by * TH + yy0 - 1, sx0 = bx * TW + xx0 - 1;
    bool ok0 = (sy0 >= 0 && sy0 < H && sx0 >= 0 && sx0 < W);
    int off0 = min(max(sy0, 0), H - 1) * W + min(max(sx0, 0), W - 1);

    int i1c = has1 ? i1 : (HALO_N - 1);
    int yy1 = i1c / HWID, xx1 = i1c - yy1 * HWID;
    int sy1 = by * TH + yy1 - 1, sx1 = bx * TW + xx1 - 1;
    bool ok1 = (sy1 >= 0 && sy1 < H && sx1 >= 0 && sx1 < W);
    int off1 = min(max(sy1, 0), H - 1) * W + min(max(sx1, 0), W - 1);

    // ---- per-k constants (broadcast loads, tiny) ----
    float wk[9], bk[9];
    #pragma unroll
    for (int k = 0; k < 9; ++k) {
        wk[k] = sigmoidf_(weight[k]);
        bk[k] = sigmoidf_(bias[k]);
    }
    const float wc = wcp[0];
    const float wm = wmp[0];

    const float* xb = x + (size_t)b * CH * H * W;

    // prefetch channel 0 halo into registers
    float r0 = xb[off0];
    float r1 = xb[off1];

    float acc = 0.0f;

    for (int c = 0; c < CH; ++c) {
        // stage sigmoid halo tile (zero outside the image — pad is AFTER sigmoid)
        sm[i0] = ok0 ? sigmoidf_(r0) : 0.0f;
        if (has1) sm[i1] = ok1 ? sigmoidf_(r1) : 0.0f;
        __syncthreads();

        // issue next channel's loads; consumed only at next iteration's store
        if (c + 1 < CH) {
            const float* xn = xb + (size_t)(c + 1) * H * W;
            r0 = xn[off0];
            r1 = xn[off1];
        }

        // gather 3x3 neighborhood
        float p[9];
        #pragma unroll
        for (int dy = 0; dy < 3; ++dy)
            #pragma unroll
            for (int dx = 0; dx < 3; ++dx)
                p[dy * 3 + dx] = sm[(ty + dy) * HWID + (tx + dx)];

        // D_k = max(w_k, p_k) + b_k ; sum
        float d[9];
        float sum = 0.0f;
        #pragma unroll
        for (int k = 0; k < 9; ++k) {
            d[k] = fmaxf(wk[k], p[k]) + bk[k];
            sum += d[k];
        }

        // median-of-9 (McGuire ShaderX6 network)
        #define S2(a,bb) { float t = d[a]; d[a] = fminf(d[a], d[bb]); d[bb] = fmaxf(t, d[bb]); }
        S2(0,3) S2(1,4) S2(2,5) S2(0,1) S2(0,2) S2(4,5) S2(3,5)   // mnmx6(0..5)
        S2(1,2) S2(3,4) S2(1,3) S2(1,6) S2(4,6) S2(2,6)           // mnmx5(1,2,3,4,6)
        S2(2,3) S2(4,7) S2(2,4) S2(3,7)                            // mnmx4(2,3,4,7)
        S2(4,8) S2(3,8) S2(3,4)                                    // mnmx3(3,4,8)
        #undef S2
        const float med = d[4];

        // out_c = wc*center + wm*median - sum - sum/9 ; accumulate over channels
        acc += wc * p[4] + wm * med - sum - sum * (1.0f / 9.0f);

        __syncthreads();   // protect sm before next iteration's overwrite
    }

    // broadcast channel-sum to all 64 output channels
    float* op = out + (size_t)b * CH * H * W + (size_t)(by * TH + ty) * W + bx * TW + tx;
    #pragma unroll
    for (int co = 0; co < CH; ++co)
        op[(size_t)co * H * W] = acc;
}

extern "C" void kernel_launch(void* const* d_in, const int* in_sizes, int n_in,
                              void* d_out, int out_size, void* d_ws, size_t ws_size,
                              hipStream_t stream) {
    const float* x      = (const float*)d_in[0];
    const float* weight = (const float*)d_in[1];
    const float* bias   = (const float*)d_in[2];
    const float* wcp    = (const float*)d_in[3];
    const float* wmp    = (const float*)d_in[4];
    float* out = (float*)d_out;

    dim3 grid(W / TW, H / TH, BATCH);   // 4 x 16 x 8 = 512 blocks
    maxsig_kernel<<<grid, 256, 0, stream>>>(x, weight, bias, wcp, wmp, out);
}

// Round 2
// 113.684 us; speedup vs baseline: 1.0277x; 1.0277x over previous
//
#include <hip/hip_runtime.h>

#define BATCH  8
#define CH     64
#define H      128
#define W      128
#define TH     4                   // tile rows per block (full-width tiles)
#define CHUNK  8                   // channels per block
#define NCHUNK (CH / CHUNK)        // 8
#define HWID   (W + 2)             // 130
#define HHGT   (TH + 2)            // 6
#define HALO_N (HWID * HHGT)       // 780
#define NSLOT  4                   // ceil(780/256)

__device__ __forceinline__ float sigmoidf_(float v) {
    return 1.0f / (1.0f + __expf(-v));
}

// Kernel 1: each block computes sum over its 8-channel chunk for a 128x4 pixel
// tile, writes the partial sum (non-atomic, exclusive) into output plane
// out[b, chunk, :, :]. Planes 0..7 serve as scratch; kernel 2 overwrites all.
__global__ __launch_bounds__(256) void partial_kernel(
    const float* __restrict__ x,
    const float* __restrict__ weight,
    const float* __restrict__ bias,
    const float* __restrict__ wcp,
    const float* __restrict__ wmp,
    float* __restrict__ out)
{
    __shared__ float sm[HALO_N];

    const int tid  = threadIdx.x;
    const int tx   = tid & (W - 1);          // 0..127
    const int ty0  = (tid >> 7) * 2;         // 0 or 2 (each thread: 2 rows)
    const int by   = blockIdx.x;             // H/TH = 32
    const int chnk = blockIdx.y;             // NCHUNK = 8
    const int b    = blockIdx.z;             // BATCH

    // ---- channel-invariant halo-slot geometry ----
    bool has[NSLOT], ok[NSLOT];
    int  off[NSLOT];
    #pragma unroll
    for (int s = 0; s < NSLOT; ++s) {
        int i  = tid + s * 256;
        has[s] = (i < HALO_N);
        int ic = has[s] ? i : (HALO_N - 1);
        int yy = ic / HWID;
        int xx = ic - yy * HWID;
        int sy = by * TH + yy - 1;
        int sx = xx - 1;
        ok[s]  = (sy >= 0 && sy < H && sx >= 0 && sx < W);
        off[s] = min(max(sy, 0), H - 1) * W + min(max(sx, 0), W - 1);
    }

    // ---- per-k constants (broadcast scalar loads) ----
    float wk[9], bk[9];
    #pragma unroll
    for (int k = 0; k < 9; ++k) {
        wk[k] = sigmoidf_(weight[k]);
        bk[k] = sigmoidf_(bias[k]);
    }
    const float wc = wcp[0];
    const float wm = wmp[0];

    const float* xb = x + ((size_t)b * CH + chnk * CHUNK) * H * W;

    // prefetch first channel of the chunk
    float r[NSLOT];
    #pragma unroll
    for (int s = 0; s < NSLOT; ++s) r[s] = xb[off[s]];

    float acc0 = 0.0f, acc1 = 0.0f;

    for (int c = 0; c < CHUNK; ++c) {
        #pragma unroll
        for (int s = 0; s < NSLOT; ++s)
            if (has[s]) sm[tid + s * 256] = ok[s] ? sigmoidf_(r[s]) : 0.0f;
        __syncthreads();

        if (c + 1 < CHUNK) {
            const float* xn = xb + (size_t)(c + 1) * H * W;
            #pragma unroll
            for (int s = 0; s < NSLOT; ++s) r[s] = xn[off[s]];
        }

        // 4 rows x 3 cols window shared by this thread's two pixels
        float v[4][3];
        #pragma unroll
        for (int dy = 0; dy < 4; ++dy)
            #pragma unroll
            for (int dx = 0; dx < 3; ++dx)
                v[dy][dx] = sm[(ty0 + dy) * HWID + tx + dx];

        #pragma unroll
        for (int j = 0; j < 2; ++j) {
            float d[9];
            float sum = 0.0f;
            #pragma unroll
            for (int dy = 0; dy < 3; ++dy)
                #pragma unroll
                for (int dx = 0; dx < 3; ++dx) {
                    int k = dy * 3 + dx;
                    float dk = fmaxf(wk[k], v[j + dy][dx]) + bk[k];
                    d[k] = dk;
                    sum += dk;
                }
            const float center = v[j + 1][1];

            // median-of-9 (McGuire ShaderX6 network)
            #define S2(a,bb) { float t = d[a]; d[a] = fminf(d[a], d[bb]); d[bb] = fmaxf(t, d[bb]); }
            S2(0,3) S2(1,4) S2(2,5) S2(0,1) S2(0,2) S2(4,5) S2(3,5)
            S2(1,2) S2(3,4) S2(1,3) S2(1,6) S2(4,6) S2(2,6)
            S2(2,3) S2(4,7) S2(2,4) S2(3,7)
            S2(4,8) S2(3,8) S2(3,4)
            #undef S2
            const float med = d[4];

            const float r_ = wc * center + wm * med - sum - sum * (1.0f / 9.0f);
            if (j == 0) acc0 += r_; else acc1 += r_;
        }

        __syncthreads();
    }

    float* op = out + ((size_t)b * CH + chnk) * H * W
                    + (size_t)(by * TH + ty0) * W + tx;
    op[0] = acc0;
    op[W] = acc1;
}

// Kernel 2: per pixel, sum the 8 partial planes and broadcast to all 64
// output planes. Race-free: each thread reads only its own pixel's sources
// (data-dependence orders its reads before its writes), and no other thread
// touches that pixel.
__global__ __launch_bounds__(256) void broadcast_kernel(float* __restrict__ out)
{
    const int g = blockIdx.x * 256 + threadIdx.x;   // [0, B*H*W)
    const int b = g >> 14;                          // H*W = 16384
    const int p = g & 16383;
    float* base = out + (size_t)b * CH * H * W;

    float s = 0.0f;
    #pragma unroll
    for (int k = 0; k < NCHUNK; ++k)
        s += base[(size_t)k * H * W + p];

    #pragma unroll
    for (int co = 0; co < CH; ++co)
        base[(size_t)co * H * W + p] = s;
}

extern "C" void kernel_launch(void* const* d_in, const int* in_sizes, int n_in,
                              void* d_out, int out_size, void* d_ws, size_t ws_size,
                              hipStream_t stream) {
    const float* x      = (const float*)d_in[0];
    const float* weight = (const float*)d_in[1];
    const float* bias   = (const float*)d_in[2];
    const float* wcp    = (const float*)d_in[3];
    const float* wmp    = (const float*)d_in[4];
    float* out = (float*)d_out;

    dim3 grid1(H / TH, NCHUNK, BATCH);            // 32 x 8 x 8 = 2048 blocks
    partial_kernel<<<grid1, 256, 0, stream>>>(x, weight, bias, wcp, wmp, out);

    const int npix = BATCH * H * W;               // 131072
    broadcast_kernel<<<npix / 256, 256, 0, stream>>>(out);   // 512 blocks
}